// Round 9
// baseline (263.140 us; speedup 1.0000x reference)
//
#include <hip/hip_runtime.h>
#include <hip/hip_bf16.h>
#include <math.h>

// ---------------------------------------------------------------------------
// Swin Transformer 3D block, MI355X (gfx950)
// B=1, D=16, H=56, W=56, C=128, NH=4, HEAD=32, window 8x7x7 (N=392), shift 4,3,3
// Round 9: (a) combined bias+mask table cbias[h][8types][392][392] (aliases
// hid) — attn inner loop is now load-add-fmax, no mask VALU, no rid staging;
// (b) LN2 fused into proj GEMM epilogue via LDS tile (row-coalesced I/O).
// attn back to best-known 4-wave/256-thread config.
// ---------------------------------------------------------------------------

typedef short s16x8 __attribute__((ext_vector_type(8)));
typedef unsigned short u16x8 __attribute__((ext_vector_type(8)));
typedef float fp32x4 __attribute__((ext_vector_type(4)));

#define T_TOT 50176      // total tokens = 128 windows * 392
#define N_TOK 392
#define N_WIN 128
#define NN2 153664       // 392*392

__device__ __forceinline__ unsigned short f2bf(float f) {
    union { float f; unsigned u; } v; v.f = f;
    unsigned r = v.u + 0x7FFFu + ((v.u >> 16) & 1u);   // RNE
    return (unsigned short)(r >> 16);
}
__device__ __forceinline__ float bf2f(unsigned short u) {
    union { unsigned u; float f; } v; v.u = ((unsigned)u) << 16;
    return v.f;
}

// ---------------------------------------------------------------------------
// Weight fp32 -> bf16 conversion
// ---------------------------------------------------------------------------
__global__ void cvt_w_k(const float* __restrict__ wq, const float* __restrict__ wp,
                        const float* __restrict__ w1, const float* __restrict__ w2,
                        unsigned short* __restrict__ oq, unsigned short* __restrict__ op,
                        unsigned short* __restrict__ o1, unsigned short* __restrict__ o2)
{
    int i = blockIdx.x * 256 + threadIdx.x;
    if (i < 384 * 128) oq[i] = f2bf(wq[i]);
    if (i < 128 * 128) op[i] = f2bf(wp[i]);
    if (i < 512 * 128) { o1[i] = f2bf(w1[i]); o2[i] = f2bf(w2[i]); }
}

// ---------------------------------------------------------------------------
// Combined bias+mask: cbias[h][type][i][j], type = isD*4 + isH*2 + isW
// mask(type,i,j) = -100 if region ids differ under that window type.
// ---------------------------------------------------------------------------
__global__ void bias_tab_k(const float* __restrict__ tab, float* __restrict__ out)
{
    int idx = blockIdx.x * 256 + threadIdx.x;
    if (idx >= 32 * NN2) return;
    int ht = idx / NN2, r = idx % NN2;
    int h = ht >> 3, type = ht & 7;
    int i = r / N_TOK, j = r % N_TOK;
    int di = i / 49, hi = (i % 49) / 7, wi = i % 7;
    int dj = j / 49, hj = (j % 49) / 7, wj = j % 7;
    int rel = (di - dj + 7) * 169 + (hi - hj + 6) * 13 + (wi - wj + 6);
    float v = tab[rel * 4 + h];
    int ri = ((type & 4) ? (di < 4 ? 9 : 18) : 0) +
             ((type & 2) ? (hi < 4 ? 3 : 6) : 0) +
             ((type & 1) ? (wi < 4 ? 1 : 2) : 0);
    int rj = ((type & 4) ? (dj < 4 ? 9 : 18) : 0) +
             ((type & 2) ? (hj < 4 ? 3 : 6) : 0) +
             ((type & 1) ? (wj < 4 ? 1 : 2) : 0);
    if (ri != rj) v -= 100.f;
    out[idx] = v;
}

// ---------------------------------------------------------------------------
// LN1 + cyclic shift (roll -4,-3,-3) + window partition -> bf16 (T_TOT,128)
// ---------------------------------------------------------------------------
__global__ __launch_bounds__(256) void ln1_part_k(
    const float* __restrict__ x, const float* __restrict__ w,
    const float* __restrict__ b, unsigned short* __restrict__ xw)
{
    const int t = blockIdx.x * 4 + (threadIdx.x >> 6);
    const int lane = threadIdx.x & 63;
    const int win = t / N_TOK, n = t % N_TOK;
    const int wd = win >> 6, wh = (win >> 3) & 7, ww = win & 7;
    const int td = n / 49, rr = n % 49, th = rr / 7, tw = rr % 7;
    const int gd = wd * 8 + td, gh = wh * 7 + th, gw = ww * 7 + tw;
    const int sd = (gd + 4) & 15;
    int sh = gh + 3; if (sh >= 56) sh -= 56;
    int sw = gw + 3; if (sw >= 56) sw -= 56;
    const float* px = x + (((size_t)sd * 56 + sh) * 56 + sw) * 128;
    float v0 = px[lane], v1 = px[lane + 64];
    float s = v0 + v1, s2 = v0 * v0 + v1 * v1;
#pragma unroll
    for (int o = 32; o > 0; o >>= 1) { s += __shfl_xor(s, o); s2 += __shfl_xor(s2, o); }
    float mu = s * (1.f / 128.f);
    float var = s2 * (1.f / 128.f) - mu * mu;
    float rstd = rsqrtf(var + 1e-5f);
    unsigned short* po = xw + (size_t)t * 128;
    po[lane]      = f2bf((v0 - mu) * rstd * w[lane]      + b[lane]);
    po[lane + 64] = f2bf((v1 - mu) * rstd * w[lane + 64] + b[lane + 64]);
}

// ---------------------------------------------------------------------------
// bf16 MFMA GEMM, 128x128 tile, 4 waves (2x2), 64x64 per wave, BK=64.
// EPI: 0 qkv | 1 proj + residual + fused LN2 (outp=x1 f32, outp2=xn bf16)
//      2 fc1+gelu | 3 fc2+residual
// ---------------------------------------------------------------------------
template<int K, int EPI>
__global__ __launch_bounds__(256, 2) void gemm_k(
    const unsigned short* __restrict__ A,
    const unsigned short* __restrict__ Bt,
    const float* __restrict__ bias,
    const float* __restrict__ resid,
    const float* __restrict__ lnw,
    const float* __restrict__ lnb,
    void* __restrict__ outp,
    void* __restrict__ outp2)
{
    constexpr int SMB = (EPI == 1) ? (128 * 132 * 4) : (2 * 128 * 64 * 2);
    __shared__ __align__(16) char smem[SMB];
    unsigned short* Asl = (unsigned short*)smem;
    unsigned short* Bsl = Asl + 128 * 64;
    const int bm = blockIdx.x * 128;
    const int bn = blockIdx.y * 128;
    const int tid = threadIdx.x;
    const int lane = tid & 63;
    const int wave = tid >> 6;
    const int wr = wave >> 1, wc = wave & 1;
    const int lr = lane & 15;
    const int lk = (lane >> 4) << 3;

    fp32x4 acc[4][4];
#pragma unroll
    for (int i = 0; i < 4; ++i)
#pragma unroll
        for (int j = 0; j < 4; ++j) acc[i][j] = {0.f, 0.f, 0.f, 0.f};

    for (int ks = 0; ks < K; ks += 64) {
        __syncthreads();
#pragma unroll
        for (int it = 0; it < 4; ++it) {
            int chunk = it * 256 + tid;
            int row = chunk >> 3;
            int kc = (chunk & 7) << 3;
            *(uint4*)&Asl[row * 64 + kc] =
                *(const uint4*)&A[(size_t)(bm + row) * K + ks + kc];
            *(uint4*)&Bsl[row * 64 + kc] =
                *(const uint4*)&Bt[(size_t)(bn + row) * K + ks + kc];
        }
        __syncthreads();
#pragma unroll
        for (int kk = 0; kk < 64; kk += 32) {
            s16x8 af[4], bfr[4];
#pragma unroll
            for (int mb = 0; mb < 4; ++mb)
                af[mb] = *(const s16x8*)&Asl[(wr * 64 + mb * 16 + lr) * 64 + kk + lk];
#pragma unroll
            for (int nb = 0; nb < 4; ++nb)
                bfr[nb] = *(const s16x8*)&Bsl[(wc * 64 + nb * 16 + lr) * 64 + kk + lk];
#pragma unroll
            for (int mb = 0; mb < 4; ++mb)
#pragma unroll
                for (int nb = 0; nb < 4; ++nb)
                    acc[mb][nb] = __builtin_amdgcn_mfma_f32_16x16x32_bf16(
                        af[mb], bfr[nb], acc[mb][nb], 0, 0, 0);
        }
    }

    const int crow = (lane >> 4) << 2;
    const int ccol = lane & 15;

    if (EPI == 1) {
        // phase 1: gemm+bias -> LDS tile [128][132] f32
        float* xs = (float*)smem;
        __syncthreads();          // drain MFMA ds_reads before overwrite
#pragma unroll
        for (int mb = 0; mb < 4; ++mb)
#pragma unroll
            for (int nb = 0; nb < 4; ++nb)
#pragma unroll
                for (int r = 0; r < 4; ++r) {
                    int row = wr * 64 + mb * 16 + crow + r;
                    int col = wc * 64 + nb * 16 + ccol;
                    xs[row * 132 + col] = acc[mb][nb][r] + bias[col];
                }
        __syncthreads();
        // phase 2: per-row residual add + LN2, coalesced I/O
        const float wA = lnw[lane], wB = lnw[lane + 64];
        const float bA = lnb[lane], bB = lnb[lane + 64];
        float* x1o = (float*)outp;
        unsigned short* xno = (unsigned short*)outp2;
        for (int row = wave; row < 128; row += 4) {
            const int grow = bm + row;
            const int w = grow / N_TOK, n = grow % N_TOK;
            const int wd = w >> 6, wh = (w >> 3) & 7, ww = w & 7;
            const int td = n / 49, rr = n % 49, th = rr / 7, tw = rr % 7;
            const int gd = wd * 8 + td, gh = wh * 7 + th, gw = ww * 7 + tw;
            const int sd = (gd + 4) & 15;
            int sh = gh + 3; if (sh >= 56) sh -= 56;
            int sw = gw + 3; if (sw >= 56) sw -= 56;
            const size_t tok = ((size_t)sd * 56 + sh) * 56 + sw;
            float w0 = xs[row * 132 + lane]      + resid[tok * 128 + lane];
            float w1 = xs[row * 132 + 64 + lane] + resid[tok * 128 + 64 + lane];
            float s = w0 + w1, s2 = w0 * w0 + w1 * w1;
#pragma unroll
            for (int o = 32; o > 0; o >>= 1) { s += __shfl_xor(s, o); s2 += __shfl_xor(s2, o); }
            float mu = s * (1.f / 128.f);
            float var = s2 * (1.f / 128.f) - mu * mu;
            float rstd = rsqrtf(var + 1e-5f);
            x1o[tok * 128 + lane]      = w0;
            x1o[tok * 128 + 64 + lane] = w1;
            xno[tok * 128 + lane]      = f2bf((w0 - mu) * rstd * wA + bA);
            xno[tok * 128 + 64 + lane] = f2bf((w1 - mu) * rstd * wB + bB);
        }
        return;
    }

#pragma unroll
    for (int mb = 0; mb < 4; ++mb) {
#pragma unroll
        for (int nb = 0; nb < 4; ++nb) {
#pragma unroll
            for (int r = 0; r < 4; ++r) {
                const int grow = bm + wr * 64 + mb * 16 + crow + r;
                const int gcol = bn + wc * 64 + nb * 16 + ccol;
                float v = acc[mb][nb][r] + bias[gcol];
                if (EPI == 0) {
                    if (gcol < 128) v *= 0.17677669529663687f;   // HEAD^-0.5
                    ((unsigned short*)outp)[(size_t)grow * 384 + gcol] = f2bf(v);
                } else if (EPI == 2) {
                    v = 0.5f * v * (1.f + erff(v * 0.70710678118654752f));
                    ((unsigned short*)outp)[(size_t)grow * 512 + gcol] = f2bf(v);
                } else {
                    size_t oi = (size_t)grow * 128 + gcol;
                    ((float*)outp)[oi] = v + resid[oi];
                }
            }
        }
    }
}

// ---------------------------------------------------------------------------
// MFMA attention v5: one block per (window, head) = 512 blocks, 4 waves.
// Swapped QK^T; softmax lane-local; combined bias+mask table (no mask VALU).
// LDS 65.5KB => 2 blocks/CU.
// ---------------------------------------------------------------------------
#define KSTR 40
#define VSTR 424
#define PTS  40

__global__ __launch_bounds__(256, 2) void attn_k(
    const unsigned short* __restrict__ qkv,
    const float* __restrict__ cbias,
    unsigned short* __restrict__ y)
{
    __shared__ __align__(16) unsigned short Ksh[416 * KSTR];
    __shared__ __align__(16) unsigned short Vt[32 * VSTR];
    __shared__ __align__(16) unsigned short Pt[4][16 * PTS];

    const int blk = blockIdx.x;
    const int wI = blk >> 2, h = blk & 3;
    const int tid = threadIdx.x;
    const int wave = tid >> 6, lane = tid & 63;
    const int lr = lane & 15, g = lane >> 4, lk = g << 3;
    const unsigned short* base = qkv + (size_t)wI * N_TOK * 384;

    const int wd = wI >> 6, wh = (wI >> 3) & 7, ww = wI & 7;
    const int type = ((wd == 1) ? 4 : 0) | ((wh == 7) ? 2 : 0) | ((ww == 7) ? 1 : 0);

    // ---- stage K natural [token][chan] ----
    for (int idx = tid; idx < 392 * 4; idx += 256) {
        int j = idx >> 2, c0 = (idx & 3) << 3;
        *(uint4*)&Ksh[j * KSTR + c0] =
            *(const uint4*)&base[(size_t)j * 384 + 128 + h * 32 + c0];
    }
    for (int idx = tid; idx < 24 * 4; idx += 256) {       // zero pad rows
        int j = 392 + (idx >> 2), c0 = (idx & 3) << 3;
        u16x8 z = {};
        *(u16x8*)&Ksh[j * KSTR + c0] = z;
    }
    // ---- stage V transposed [chan][token] (scalar gather, latency-hidden) ----
    for (int idx = tid; idx < 32 * 49; idx += 256) {
        int c = idx & 31, j0v = (idx >> 5) << 3;
        const unsigned short* vp = base + 256 + h * 32 + c;
        u16x8 tmp;
#pragma unroll
        for (int i = 0; i < 8; ++i) tmp[i] = vp[(size_t)(j0v + i) * 384];
        *(u16x8*)&Vt[c * VSTR + j0v] = tmp;
    }
    for (int idx = tid; idx < 32 * 3; idx += 256) {       // zero pad cols
        int c = idx & 31, j0v = 392 + ((idx >> 5) << 3);
        u16x8 z = {};
        *(u16x8*)&Vt[c * VSTR + j0v] = z;
    }
    __syncthreads();

    const float* cbb = cbias + (size_t)(h * 8 + type) * NN2;
    unsigned short* pw = &Pt[wave][0];
    const int j0 = g << 2;

    for (int rt = wave; rt < 25; rt += 4) {
        // ---- swapped QK^T: lane (g,lr) holds S[i=lr][j=ct*16+g*4+r] ----
        const int irow = rt * 16 + lr;
        const int ic = (irow < 392) ? irow : 391;
        s16x8 bq = *(const s16x8*)&base[(size_t)ic * 384 + h * 32 + lk];
        fp32x4 acc[25];
#pragma unroll
        for (int ct = 0; ct < 25; ++ct) {
            s16x8 ak = *(const s16x8*)&Ksh[(ct * 16 + lr) * KSTR + lk];
            fp32x4 z = {0.f, 0.f, 0.f, 0.f};
            acc[ct] = __builtin_amdgcn_mfma_f32_16x16x32_bf16(ak, bq, z, 0, 0, 0);
        }
        // ---- combined bias+mask (float4) + row max (in-lane) ----
        const float* cbr = cbb + (size_t)ic * N_TOK;
        float mx = -1e30f;
#pragma unroll
        for (int ct = 0; ct < 24; ++ct) {
            float4 bv = *(const float4*)&cbr[ct * 16 + j0];
            acc[ct][0] += bv.x; acc[ct][1] += bv.y;
            acc[ct][2] += bv.z; acc[ct][3] += bv.w;
            mx = fmaxf(mx, fmaxf(fmaxf(acc[ct][0], acc[ct][1]),
                                 fmaxf(acc[ct][2], acc[ct][3])));
        }
        {   // ct = 24: j = 384 + g*4 + r, valid only for g < 2
            if (g < 2) {
                float4 bv = *(const float4*)&cbr[384 + j0];
                acc[24][0] += bv.x; acc[24][1] += bv.y;
                acc[24][2] += bv.z; acc[24][3] += bv.w;
                mx = fmaxf(mx, fmaxf(fmaxf(acc[24][0], acc[24][1]),
                                     fmaxf(acc[24][2], acc[24][3])));
            } else {
                acc[24][0] = acc[24][1] = acc[24][2] = acc[24][3] = -1e30f;
            }
        }
        mx = fmaxf(mx, __shfl_xor(mx, 16));
        mx = fmaxf(mx, __shfl_xor(mx, 32));
        // ---- exp + row sum (in-lane + 2 shfl) ----
        float sum = 0.f;
#pragma unroll
        for (int ct = 0; ct < 25; ++ct)
#pragma unroll
            for (int r = 0; r < 4; ++r) {
                float p = __expf(acc[ct][r] - mx);
                acc[ct][r] = p;
                sum += p;
            }
        sum += __shfl_xor(sum, 16);
        sum += __shfl_xor(sum, 32);
        const float rs = 1.f / sum;
        // ---- PV: per k-step, transpose P through per-wave LDS tile ----
        fp32x4 o0 = {0.f, 0.f, 0.f, 0.f}, o1 = {0.f, 0.f, 0.f, 0.f};
#pragma unroll
        for (int ks = 0; ks < 13; ++ks) {
            unsigned w0, w1, w2 = 0, w3 = 0;
            asm("v_cvt_pk_bf16_f32 %0, %1, %2"
                : "=v"(w0) : "v"(acc[2 * ks][0]), "v"(acc[2 * ks][1]));
            asm("v_cvt_pk_bf16_f32 %0, %1, %2"
                : "=v"(w1) : "v"(acc[2 * ks][2]), "v"(acc[2 * ks][3]));
            if (ks < 12) {
                asm("v_cvt_pk_bf16_f32 %0, %1, %2"
                    : "=v"(w2) : "v"(acc[2 * ks + 1][0]), "v"(acc[2 * ks + 1][1]));
                asm("v_cvt_pk_bf16_f32 %0, %1, %2"
                    : "=v"(w3) : "v"(acc[2 * ks + 1][2]), "v"(acc[2 * ks + 1][3]));
            }
            *(unsigned*)&pw[lr * PTS + j0]          = w0;
            *(unsigned*)&pw[lr * PTS + j0 + 2]      = w1;
            *(unsigned*)&pw[lr * PTS + 16 + j0]     = w2;
            *(unsigned*)&pw[lr * PTS + 16 + j0 + 2] = w3;
            s16x8 ap  = *(const s16x8*)&pw[lr * PTS + lk];
            s16x8 bv0 = *(const s16x8*)&Vt[lr * VSTR + ks * 32 + lk];
            s16x8 bv1 = *(const s16x8*)&Vt[(16 + lr) * VSTR + ks * 32 + lk];
            o0 = __builtin_amdgcn_mfma_f32_16x16x32_bf16(ap, bv0, o0, 0, 0, 0);
            o1 = __builtin_amdgcn_mfma_f32_16x16x32_bf16(ap, bv1, o1, 0, 0, 0);
        }
        // ---- write O (normalize by row sums fetched via shfl) ----
#pragma unroll
        for (int r = 0; r < 4; ++r) {
            const float rsr = __shfl(rs, (g << 2) + r);
            const int row = rt * 16 + (g << 2) + r;
            if (row < 392) {
                size_t ob = ((size_t)wI * N_TOK + row) * 128 + h * 32;
                y[ob + lr]      = f2bf(o0[r] * rsr);
                y[ob + 16 + lr] = f2bf(o1[r] * rsr);
            }
        }
    }
}

// ---------------------------------------------------------------------------
extern "C" void kernel_launch(void* const* d_in, const int* in_sizes, int n_in,
                              void* d_out, int out_size, void* d_ws, size_t ws_size,
                              hipStream_t stream)
{
    const float* x      = (const float*)d_in[0];
    const float* n1w    = (const float*)d_in[1];
    const float* n1b    = (const float*)d_in[2];
    const float* qkv_w  = (const float*)d_in[3];
    const float* qkv_b  = (const float*)d_in[4];
    const float* rpt    = (const float*)d_in[5];
    const float* proj_w = (const float*)d_in[6];
    const float* proj_b = (const float*)d_in[7];
    const float* n2w    = (const float*)d_in[8];
    const float* n2b    = (const float*)d_in[9];
    const float* fc1_w  = (const float*)d_in[10];
    const float* fc1_b  = (const float*)d_in[11];
    const float* fc2_w  = (const float*)d_in[12];
    const float* fc2_b  = (const float*)d_in[13];

    char* ws = (char*)d_ws;
    unsigned short* xw  = (unsigned short*)(ws);                  // T*128 bf16
    unsigned short* qkv = (unsigned short*)(ws + 12845056);       // T*384 bf16
    unsigned short* y   = (unsigned short*)(ws + 51380224);       // T*128 bf16
    float*          x1  = (float*)         (ws + 64225280);       // T*128 f32
    unsigned short* xn  = (unsigned short*)(ws + 89915392);       // T*128 bf16
    unsigned short* hid = (unsigned short*)(ws + 102760448);      // T*512 bf16 (fc1->fc2)
    float*          cb  = (float*)         (ws + 102760448);      // aliases hid: 4*8*392*392 f32, dead before fc1
    unsigned short* wq  = (unsigned short*)(ws + 154140672);      // 384*128 bf16
    unsigned short* wp  = (unsigned short*)(ws + 154238976);      // 128*128 bf16
    unsigned short* w1  = (unsigned short*)(ws + 154271744);      // 512*128 bf16
    unsigned short* w2  = (unsigned short*)(ws + 154402816);      // 128*512 bf16

    hipLaunchKernelGGL(cvt_w_k, dim3(256), dim3(256), 0, stream,
                       qkv_w, proj_w, fc1_w, fc2_w, wq, wp, w1, w2);
    hipLaunchKernelGGL(bias_tab_k, dim3((32 * NN2 + 255) / 256), dim3(256),
                       0, stream, rpt, cb);
    hipLaunchKernelGGL(ln1_part_k, dim3(T_TOT / 4), dim3(256), 0, stream,
                       x, n1w, n1b, xw);
    hipLaunchKernelGGL((gemm_k<128, 0>), dim3(392, 3), dim3(256), 0, stream,
                       xw, wq, qkv_b, (const float*)nullptr,
                       (const float*)nullptr, (const float*)nullptr,
                       (void*)qkv, (void*)nullptr);
    hipLaunchKernelGGL(attn_k, dim3(512), dim3(256), 0, stream, qkv, cb, y);
    hipLaunchKernelGGL((gemm_k<128, 1>), dim3(392, 1), dim3(256), 0, stream,
                       y, wp, proj_b, x, n2w, n2b, (void*)x1, (void*)xn);
    hipLaunchKernelGGL((gemm_k<128, 2>), dim3(392, 4), dim3(256), 0, stream,
                       xn, w1, fc1_b, (const float*)nullptr,
                       (const float*)nullptr, (const float*)nullptr,
                       (void*)hid, (void*)nullptr);
    hipLaunchKernelGGL((gemm_k<512, 3>), dim3(392, 1), dim3(256), 0, stream,
                       hid, w2, fc2_b, x1,
                       (const float*)nullptr, (const float*)nullptr,
                       d_out, (void*)nullptr);
}